// Round 7
// baseline (71.585 us; speedup 1.0000x reference)
//
#include <hip/hip_runtime.h>

#define NPTS  131072        // B*G
#define GPTS  32768         // G
#define NCELL 262144        // 4 * 256 * 256
#define ZROW  262144        // zero row index in cfb

typedef __attribute__((ext_vector_type(8)))  _Float16 half8v;
typedef __attribute__((ext_vector_type(16))) float    f32x16;

// ---- sigmoid emulating the reference f32 pipeline (bit-faithful) ----------
__device__ __forceinline__ float sigf(float x) {
    x = fminf(fmaxf(x, -9.21f), 9.21f);
    float t = (float)exp(-(double)x);
    return 1.0f / (1.0f + t);
}

// ---- fused front-end -------------------------------------------------------
// blocks [0,512):  sigmoid + per-block min + rulebook-grid clear
// blocks [512,530): W -> 32x32x16 f16 B-fragments
__global__ __launch_bounds__(256) void k_front(const float* __restrict__ anchor,
                                               const float* __restrict__ W,
                                               float* __restrict__ s0a,
                                               float* __restrict__ s1a,
                                               float2* __restrict__ blockmin,
                                               _Float16* __restrict__ bpk,
                                               int* __restrict__ grd) {
    const int bid = blockIdx.x;
    if (bid < 512) {
        __shared__ float red[8];
        int i = bid * 256 + threadIdx.x;            // [0,131072)
        int2 mone = {-1, -1};
        ((int2*)grd)[i] = mone;                     // clear 1 MB rulebook grid
        float2 a = ((const float2*)anchor)[i];
        float s0 = sigf(a.x);
        float s1 = sigf(a.y);
        s0a[i] = s0;
        s1a[i] = s1;
        float m0 = s0, m1 = s1;
        #pragma unroll
        for (int off = 32; off; off >>= 1) {
            m0 = fminf(m0, __shfl_down(m0, off));
            m1 = fminf(m1, __shfl_down(m1, off));
        }
        int wv = threadIdx.x >> 6;
        if ((threadIdx.x & 63) == 0) { red[wv * 2] = m0; red[wv * 2 + 1] = m1; }
        __syncthreads();
        if (threadIdx.x == 0) {
            float a0 = fminf(fminf(red[0], red[2]), fminf(red[4], red[6]));
            float a1 = fminf(fminf(red[1], red[3]), fminf(red[5], red[7]));
            blockmin[bid] = make_float2(a0, a1);
        }
    } else {
        // frag q = t*8 + ks*2 + nt; lane l: B[k=ks*16+(l>>5)*8+j][n=nt*32+(l&31)]
        int tid = (bid - 512) * 256 + threadIdx.x;
        if (tid >= 4608) return;
        int l  = tid & 63;
        int q  = tid >> 6;
        int nt = q & 1;
        int ks = (q >> 1) & 3;
        int t  = q >> 3;
        int n  = nt * 32 + (l & 31);
        int kb = ks * 16 + (l >> 5) * 8;
        half8v v;
        #pragma unroll
        for (int j = 0; j < 8; ++j)
            v[j] = (_Float16)W[(t * 64 + kb + j) * 64 + n];
        ((half8v*)bpk)[q * 64 + l] = v;
    }
}

// ---- cell index + rulebook scatter (max id wins); min-fold at head --------
__global__ __launch_bounds__(256) void k_grid(const float* __restrict__ s0a,
                                              const float* __restrict__ s1a,
                                              const float2* __restrict__ blockmin,
                                              int* __restrict__ pidx,
                                              int* __restrict__ grid) {
    __shared__ float red[8];
    float2 ba = blockmin[threadIdx.x];
    float2 bb = blockmin[threadIdx.x + 256];
    float m0 = fminf(ba.x, bb.x), m1 = fminf(ba.y, bb.y);
    #pragma unroll
    for (int off = 32; off; off >>= 1) {
        m0 = fminf(m0, __shfl_down(m0, off));
        m1 = fminf(m1, __shfl_down(m1, off));
    }
    int wv = threadIdx.x >> 6;
    if ((threadIdx.x & 63) == 0) { red[wv * 2] = m0; red[wv * 2 + 1] = m1; }
    __syncthreads();
    m0 = fminf(fminf(red[0], red[2]), fminf(red[4], red[6]));
    m1 = fminf(fminf(red[1], red[3]), fminf(red[5], red[7]));

    int i = blockIdx.x * 256 + threadIdx.x;
    int iy = (int)((s0a[i] - m0) * 256.0f);
    int ix = (int)((s1a[i] - m1) * 256.0f);
    pidx[i] = (iy << 8) | ix;
    int b = i >> 15;
    atomicMax(&grid[(b << 16) + (iy << 8) + ix], i);
}

// ---- cell-major winner-feature table: cfb[cell] = f16 feats of grid winner -
// (zeros for empty cells; row ZROW = zeros for out-of-bounds taps)
__global__ __launch_bounds__(256) void k_fill(const float* __restrict__ feats,
                                              const int* __restrict__ grd,
                                              _Float16* __restrict__ cfb) {
    int c = blockIdx.x * 256 + threadIdx.x;         // [0, NCELL)
    int nid = grd[c];
    _Float16* dst = cfb + ((long)c << 6);
    if (nid >= 0) {
        const float4* src = (const float4*)(feats + ((long)nid << 6));
        #pragma unroll
        for (int q = 0; q < 8; ++q) {
            float4 f = src[2 * q];
            float4 g = src[2 * q + 1];
            half8v o = {(_Float16)f.x, (_Float16)f.y, (_Float16)f.z, (_Float16)f.w,
                        (_Float16)g.x, (_Float16)g.y, (_Float16)g.z, (_Float16)g.w};
            ((half8v*)dst)[q] = o;
        }
    } else {
        half8v z = {};
        #pragma unroll
        for (int q = 0; q < 8; ++q) ((half8v*)dst)[q] = z;
    }
    if (c == 0) {                                    // zero row for OOB taps
        half8v z = {};
        _Float16* zr = cfb + ((long)ZROW << 6);
        #pragma unroll
        for (int q = 0; q < 8; ++q) ((half8v*)zr)[q] = z;
    }
}

// ---- MFMA conv: wave = 32 points x 64 couts; one-hop cfb gathers ----------
// A-frag: lane l holds A[row=l&31][k=ks*16+(l>>5)*8+j] -> 16B loads from cfb row
// C/D: col=lane&31, row=(reg&3)+8*(reg>>2)+4*(lane>>5)   [HW-verified]
__global__ __launch_bounds__(256, 4) void k_mconv(const _Float16* __restrict__ cfb,
                                                  const _Float16* __restrict__ bpk,
                                                  const int* __restrict__ pidx,
                                                  float* __restrict__ out) {
    const int lane  = threadIdx.x & 63;
    const int wv    = threadIdx.x >> 6;
    const int pbase = (blockIdx.x << 7) + (wv << 5);
    const int prow  = lane & 31;
    const int khalf = lane >> 5;
    const int p     = pbase + prow;

    const int pk = pidx[p];
    const int iy = pk >> 8;
    const int ix = pk & 255;
    const int bbase = (p >> 15) << 16;

    int row[9];
    #pragma unroll
    for (int t = 0; t < 9; ++t) {
        const int ny = iy + t / 3 - 1;
        const int nx = ix + t % 3 - 1;
        row[t] = ((unsigned)ny < 256u && (unsigned)nx < 256u)
                   ? bbase + (ny << 8) + nx : ZROW;
    }

    const half8v* bq = (const half8v*)bpk + lane;

    f32x16 acc0, acc1;
    #pragma unroll
    for (int r = 0; r < 16; ++r) { acc0[r] = 0.0f; acc1[r] = 0.0f; }

    #pragma unroll
    for (int t = 0; t < 9; ++t) {
        const half8v* arow = (const half8v*)(cfb + ((long)row[t] << 6));
        half8v a0 = arow[khalf];
        half8v a1 = arow[2 + khalf];
        half8v a2 = arow[4 + khalf];
        half8v a3 = arow[6 + khalf];
        const half8v* bt = bq + (t << 9);          // 8 frags * 64 lanes per tap
        acc0 = __builtin_amdgcn_mfma_f32_32x32x16_f16(a0, bt[0 * 64], acc0, 0, 0, 0);
        acc1 = __builtin_amdgcn_mfma_f32_32x32x16_f16(a0, bt[1 * 64], acc1, 0, 0, 0);
        acc0 = __builtin_amdgcn_mfma_f32_32x32x16_f16(a1, bt[2 * 64], acc0, 0, 0, 0);
        acc1 = __builtin_amdgcn_mfma_f32_32x32x16_f16(a1, bt[3 * 64], acc1, 0, 0, 0);
        acc0 = __builtin_amdgcn_mfma_f32_32x32x16_f16(a2, bt[4 * 64], acc0, 0, 0, 0);
        acc1 = __builtin_amdgcn_mfma_f32_32x32x16_f16(a2, bt[5 * 64], acc1, 0, 0, 0);
        acc0 = __builtin_amdgcn_mfma_f32_32x32x16_f16(a3, bt[6 * 64], acc0, 0, 0, 0);
        acc1 = __builtin_amdgcn_mfma_f32_32x32x16_f16(a3, bt[7 * 64], acc1, 0, 0, 0);
    }

    #pragma unroll
    for (int r = 0; r < 16; ++r) {
        int orow = pbase + (r & 3) + ((r >> 2) << 3) + (khalf << 2);
        out[(long)orow * 64 + prow]      = acc0[r];
        out[(long)orow * 64 + 32 + prow] = acc1[r];
    }
}

extern "C" void kernel_launch(void* const* d_in, const int* in_sizes, int n_in,
                              void* d_out, int out_size, void* d_ws, size_t ws_size,
                              hipStream_t stream) {
    const float* inst   = (const float*)d_in[0]; // (B,G,64)
    const float* anchor = (const float*)d_in[1]; // (B,G,2)
    const float* W      = (const float*)d_in[2]; // (3,3,64,64)
    float* out = (float*)d_out;

    char* ws = (char*)d_ws;
    float*     s0a  = (float*)(ws);                      // 512 KB
    float*     s1a  = (float*)(ws + 524288);             // 512 KB
    int*       pidx = (int*)(ws + 1048576);              // 512 KB
    int*       grd  = (int*)(ws + 1572864);              // 1 MB
    float2*    bmin = (float2*)(ws + 2621440);           // 4 KB
    _Float16*  bpk  = (_Float16*)(ws + 2625536);         // 72 KB
    _Float16*  cfb  = (_Float16*)(ws + 2703360);         // (NCELL+1)*128 B = 33.6 MB

    k_front<<<530,  256, 0, stream>>>(anchor, W, s0a, s1a, bmin, bpk, grd);
    k_grid <<<512,  256, 0, stream>>>(s0a, s1a, bmin, pidx, grd);
    k_fill <<<1024, 256, 0, stream>>>(inst, grd, cfb);
    k_mconv<<<1024, 256, 0, stream>>>(cfb, bpk, pidx, out);
}